// Round 4
// baseline (87.963 us; speedup 1.0000x reference)
//
#include <hip/hip_runtime.h>
#include <float.h>

#define B 8
#define L 512
#define D 128
#define U 32
#define WIN 128
#define EPS 1e-7f
#define T 4                      // queries per attn block
#define ROWS (T + WIN - 1)       // 131 key-rows per block window
#define WP 9                     // odd pitch: conflict-free weight scatter

// ---------------- prep: colsum partials + folded weights ----------------
// 64 blocks; block (b,j) sums 64 rows. Block 0 additionally folds
// wq = Wt@Wa, wk = Wx@Wa, c = Wa.bh + ba into wqk[257].
__global__ __launch_bounds__(256) void prep_kernel(
        const float* __restrict__ x, const float* __restrict__ Wt,
        const float* __restrict__ Wx, const float* __restrict__ bh,
        const float* __restrict__ Wa, const float* __restrict__ ba,
        float* __restrict__ xpart, float* __restrict__ wqk) {
    __shared__ float red[256];
    int blk = blockIdx.x, tid = threadIdx.x;
    int b = blk >> 3, j = blk & 7;
    int d = tid & 127, h = tid >> 7;
    const float* xp = x + ((size_t)(b * L + j * 64 + h * 32)) * D + d;
    float s = 0.f;
#pragma unroll 8
    for (int i = 0; i < 32; ++i) s += xp[(size_t)i * D];
    red[tid] = s;
    __syncthreads();
    if (tid < 128) xpart[blk * 128 + tid] = red[tid] + red[tid + 128];

    if (blk == 0) {
        if (tid < 128) {
            float sq = 0.f;
#pragma unroll
            for (int u = 0; u < U; ++u) sq += Wt[tid * U + u] * Wa[u];
            wqk[tid] = sq;
        } else {
            int dd = tid - 128;
            float sk = 0.f;
#pragma unroll
            for (int u = 0; u < U; ++u) sk += Wx[dd * U + u] * Wa[u];
            wqk[128 + dd] = sk;
        }
        if (tid == 0) {
            float s2 = ba[0];
            for (int u = 0; u < U; ++u) s2 += bh[u] * Wa[u];
            wqk[256] = s2;
        }
    }
}

// ---------------- attn: one block per 4 queries, fully fused ----------------
// Phase 1 (score): 2 threads/row compute kd[r]=x_r.wk (and qd for the 4 query
// rows) straight from global x — also warms L1/L2 for PV.
// Phase 2 (weight): wave q handles query t0+q; lane kt covers keys kt, kt+64.
// Mask zeroes scores (not -inf): each out-of-window key weighs w0=exp(-m);
// folded exactly as w0*xsum with in-window weights pre-subtracted.
// Phase 3 (PV): wave q, h=row-half, dt=dims; shfl_xor(32) combines halves.
__global__ __launch_bounds__(256) void attn_kernel(
        const float* __restrict__ x, const float* __restrict__ wqk,
        const float* __restrict__ xpart, float* __restrict__ out) {
    __shared__ float swq[D], swk[D];
    __shared__ float kds[ROWS];
    __shared__ float qds[T];
    __shared__ float w[ROWS * WP];
    __shared__ float adj[T];
    int blk = blockIdx.x;
    int b = blk >> 7;                 // L/T = 128 tiles per batch
    int t0 = (blk & 127) * T;
    int row0 = t0 - (WIN / 2 - 1);    // t0 - 63
    int tid = threadIdx.x;
    int rlo = max(0, -row0);
    int rhi = min(ROWS, L - row0);

    if (tid < 128) swq[tid] = wqk[tid];
    else           swk[tid - 128] = wqk[tid];
    float cval = wqk[256];
    for (int i = tid; i < ROWS * WP; i += 256) w[i] = 0.f;
    __syncthreads();

    const float4* xb4 = (const float4*)(x + (size_t)b * L * D);

    // ---- phase 1: scores ----
#pragma unroll
    for (int pass = 0; pass < 2; ++pass) {
        int r = pass * 128 + (tid >> 1);
        int h = tid & 1;
        if (r < ROWS && r >= rlo && r < rhi) {      // pair-lanes share r
            const float4* xr = xb4 + (size_t)(row0 + r) * (D / 4) + h * 16;
            float sq = 0.f, sk = 0.f;
            int d0 = h * 64;
#pragma unroll
            for (int i = 0; i < 16; ++i) {
                float4 v = xr[i];
                sq += v.x * swq[d0+4*i]   + v.y * swq[d0+4*i+1]
                    + v.z * swq[d0+4*i+2] + v.w * swq[d0+4*i+3];
                sk += v.x * swk[d0+4*i]   + v.y * swk[d0+4*i+1]
                    + v.z * swk[d0+4*i+2] + v.w * swk[d0+4*i+3];
            }
            sq += __shfl_xor(sq, 1);
            sk += __shfl_xor(sk, 1);
            if (h == 0) {
                kds[r] = sk;
                int qi = r - (WIN / 2 - 1);
                if (qi >= 0 && qi < T) qds[qi] = sq + cval;  // query rows always valid
            }
        }
    }
    __syncthreads();

    // ---- phase 2: weights ----
    {
        int q = tid >> 6, kt = tid & 63;
        int t = t0 + q;
        float qv = qds[q];
        float e[2];
        int   sv[2];
#pragma unroll
        for (int i = 0; i < 2; ++i) {
            int r = q + kt + 64 * i;
            bool valid = (r >= rlo) && (r < rhi);
            sv[i] = valid;
            e[i] = valid ? (qv + kds[r]) : -FLT_MAX;
        }
        float mx = fmaxf(e[0], e[1]);
#pragma unroll
        for (int off = 32; off > 0; off >>= 1) mx = fmaxf(mx, __shfl_xor(mx, off));
        float m = fmaxf(mx, 0.f);          // masked zeros always present (WIN < L)
        float w0 = __expf(-m);
        float wv[2], sm = 0.f;
#pragma unroll
        for (int i = 0; i < 2; ++i) {
            wv[i] = sv[i] ? __expf(e[i] - m) : 0.f;
            sm += wv[i];
        }
#pragma unroll
        for (int off = 32; off > 0; off >>= 1) sm += __shfl_xor(sm, off);
        int ss0 = max(0, t - 63), ss1 = min(L, t + 65);
        int count = ss1 - ss0;
        float inv = 1.f / (sm + (float)(L - count) * w0 + EPS);
#pragma unroll
        for (int i = 0; i < 2; ++i) {
            int r = q + kt + 64 * i;
            if (sv[i]) w[r * WP + q] = (wv[i] - w0) * inv;
        }
        if (kt == 0) adj[q] = w0 * inv;
    }
    __syncthreads();

    // ---- phase 3: PV ----
    {
        int q = tid >> 6, h = (tid >> 5) & 1, dt = tid & 31;
        int mid = rlo + ((rhi - rlo + 1) >> 1);
        int ra = h ? mid : rlo;
        int rb = h ? rhi : mid;
        float4 acc = {0.f, 0.f, 0.f, 0.f};
#pragma unroll 4
        for (int r = ra; r < rb; ++r) {
            float4 xv = xb4[(size_t)(row0 + r) * (D / 4) + dt];
            float ww = w[r * WP + q];
            acc.x += ww * xv.x; acc.y += ww * xv.y;
            acc.z += ww * xv.z; acc.w += ww * xv.w;
        }
        acc.x += __shfl_xor(acc.x, 32); acc.y += __shfl_xor(acc.y, 32);
        acc.z += __shfl_xor(acc.z, 32); acc.w += __shfl_xor(acc.w, 32);

        if (h == 0) {
            const float4* xp = (const float4*)(xpart + (size_t)(8 * b) * D);
            float sx = 0.f, sy = 0.f, sz = 0.f, sw = 0.f;
#pragma unroll
            for (int j = 0; j < 8; ++j) {
                float4 v = xp[j * 32 + dt];
                sx += v.x; sy += v.y; sz += v.z; sw += v.w;
            }
            float a = adj[q];
            float4 o = {acc.x + a * sx, acc.y + a * sy,
                        acc.z + a * sz, acc.w + a * sw};
            ((float4*)out)[((size_t)(b * L + t0 + q)) * (D / 4) + dt] = o;
        }
    }
}

extern "C" void kernel_launch(void* const* d_in, const int* in_sizes, int n_in,
                              void* d_out, int out_size, void* d_ws, size_t ws_size,
                              hipStream_t stream) {
    const float* x  = (const float*)d_in[0];
    const float* Wt = (const float*)d_in[1];
    const float* Wx = (const float*)d_in[2];
    const float* bh = (const float*)d_in[3];
    const float* Wa = (const float*)d_in[4];
    const float* ba = (const float*)d_in[5];
    float* out = (float*)d_out;

    float* ws    = (float*)d_ws;
    float* xpart = ws;                  // 64 * 128 = 8192
    float* wqk   = xpart + 64 * 128;    // 257 (wq | wk | c)

    prep_kernel<<<64, 256, 0, stream>>>(x, Wt, Wx, bh, Wa, ba, xpart, wqk);
    attn_kernel<<<B * (L / T), 256, 0, stream>>>(x, wqk, xpart, out);
}

// Round 5
// 80.026 us; speedup vs baseline: 1.0992x; 1.0992x over previous
//
#include <hip/hip_runtime.h>
#include <float.h>

#define B 8
#define L 512
#define D 128
#define U 32
#define WIN 128
#define EPS 1e-7f
#define T 4                      // queries per attn block (1 query per wave)
#define ROWS (T + WIN - 1)       // 131 key-rows per block window
#define WP 5                     // odd pitch: conflict-free weight scatter; PV reads broadcast

// ---------------- prep: scores + colsum partials (64 blocks) ----------------
// Block blk covers 64 rows [blk*64, blk*64+64).
// Scores: 4 threads/row (32-dim quarters, 8 float4 each), shfl combine.
//   qd[r] = x_r.(Wt@Wa) + (Wa.bh + ba)   (c folded in);  kd[r] = x_r.(Wx@Wa)
// Colsum: thread (c4 = tid&31 float4-col, rg = tid>>5 of 8 row-groups x 8 rows),
//   LDS tree over row-groups -> xpart[blk][128].
__global__ __launch_bounds__(256) void prep_kernel(
        const float* __restrict__ x, const float* __restrict__ Wt,
        const float* __restrict__ Wx, const float* __restrict__ bh,
        const float* __restrict__ Wa, const float* __restrict__ ba,
        float* __restrict__ qd, float* __restrict__ kd,
        float* __restrict__ xpart) {
    __shared__ float swq[D], swk[D];
    __shared__ float4 red4[8][32];
    int blk = blockIdx.x, tid = threadIdx.x;
    int row0 = blk * 64;

    // fold weights: wq = Wt@Wa, wk = Wx@Wa
    if (tid < 128) {
        float sq = 0.f;
#pragma unroll
        for (int u = 0; u < U; ++u) sq += Wt[tid * U + u] * Wa[u];
        swq[tid] = sq;
    } else {
        int dd = tid - 128;
        float sk = 0.f;
#pragma unroll
        for (int u = 0; u < U; ++u) sk += Wx[dd * U + u] * Wa[u];
        swk[dd] = sk;
    }
    // c is uniform: scalar-ALU per thread (s_load'd operands)
    float cval = ba[0];
#pragma unroll
    for (int u = 0; u < U; ++u) cval += bh[u] * Wa[u];
    __syncthreads();

    // ---- scores: 4 threads per row ----
    {
        int rl = tid >> 2, qr = tid & 3;
        int row = row0 + rl;
        const float4* xr = (const float4*)(x + (size_t)row * D) + qr * 8;
        float sq = 0.f, sk = 0.f;
        int d0 = qr * 32;
#pragma unroll
        for (int i = 0; i < 8; ++i) {
            float4 v = xr[i];
            sq += v.x * swq[d0+4*i]   + v.y * swq[d0+4*i+1]
                + v.z * swq[d0+4*i+2] + v.w * swq[d0+4*i+3];
            sk += v.x * swk[d0+4*i]   + v.y * swk[d0+4*i+1]
                + v.z * swk[d0+4*i+2] + v.w * swk[d0+4*i+3];
        }
        sq += __shfl_xor(sq, 1); sq += __shfl_xor(sq, 2);
        sk += __shfl_xor(sk, 1); sk += __shfl_xor(sk, 2);
        if (qr == 0) { qd[row] = sq + cval; kd[row] = sk; }
    }

    // ---- colsum partials: float4 columns, 8 rows per thread ----
    {
        int c4 = tid & 31, rg = tid >> 5;
        const float4* xp = (const float4*)(x + (size_t)(row0 + rg * 8) * D) + c4;
        float4 s = {0.f, 0.f, 0.f, 0.f};
#pragma unroll
        for (int i = 0; i < 8; ++i) {
            float4 v = xp[(size_t)i * (D / 4)];
            s.x += v.x; s.y += v.y; s.z += v.z; s.w += v.w;
        }
        red4[rg][c4] = s;
    }
    __syncthreads();
#pragma unroll
    for (int off = 4; off > 0; off >>= 1) {
        int c4 = tid & 31, rg = tid >> 5;
        if (rg < off) {
            float4 a = red4[rg][c4], bb = red4[rg + off][c4];
            a.x += bb.x; a.y += bb.y; a.z += bb.z; a.w += bb.w;
            red4[rg][c4] = a;
        }
        __syncthreads();
    }
    if (tid < 32) ((float4*)(xpart + (size_t)blk * D))[tid] = red4[0][tid];
}

// ---------------- attn: one block per 4 queries (1 query/wave) ----------------
// Weight phase: wave q owns query t0+q; lane kt covers keys kt, kt+64.
// Mask zeroes scores (not -inf): each out-of-window key weighs w0 = exp(-m);
// folded exactly as w0 * xsum_batch with in-window weights pre-subtracted.
// PV: wave q, h = row-half, dt = float4-dim; shfl_xor(32) combines halves.
// w reads in PV are wave-uniform broadcasts (conflict-free).
__global__ __launch_bounds__(256) void attn_kernel(
        const float* __restrict__ x, const float* __restrict__ qd,
        const float* __restrict__ kd, const float* __restrict__ xpart,
        float* __restrict__ out) {
    __shared__ float w[ROWS * WP];
    __shared__ float adj[T];
    int blk = blockIdx.x;
    int b = blk >> 7;                 // L/T = 128 tiles per batch
    int t0 = (blk & 127) * T;
    int row0 = t0 - (WIN / 2 - 1);    // t0 - 63
    int tid = threadIdx.x;
    int rlo = max(0, -row0);
    int rhi = min(ROWS, L - row0);

    for (int i = tid; i < ROWS * WP; i += 256) w[i] = 0.f;
    __syncthreads();

    // ---- weight phase ----
    {
        int q = tid >> 6, kt = tid & 63;
        int t = t0 + q;
        float qv = qd[b * L + t];
        float e[2];
        int   sv[2];
#pragma unroll
        for (int i = 0; i < 2; ++i) {
            int r = q + kt + 64 * i;          // key s = t - 63 + (kt + 64 i)
            bool valid = (r >= rlo) && (r < rhi);
            sv[i] = valid;
            e[i] = valid ? (qv + kd[b * L + row0 + r]) : -FLT_MAX;
        }
        float mx = fmaxf(e[0], e[1]);
#pragma unroll
        for (int off = 32; off > 0; off >>= 1) mx = fmaxf(mx, __shfl_xor(mx, off));
        float m = fmaxf(mx, 0.f);          // masked zeros always present (WIN < L)
        float w0 = __expf(-m);
        float wv[2], sm = 0.f;
#pragma unroll
        for (int i = 0; i < 2; ++i) {
            wv[i] = sv[i] ? __expf(e[i] - m) : 0.f;
            sm += wv[i];
        }
#pragma unroll
        for (int off = 32; off > 0; off >>= 1) sm += __shfl_xor(sm, off);
        int ss0 = max(0, t - 63), ss1 = min(L, t + 65);
        int count = ss1 - ss0;
        float inv = 1.f / (sm + (float)(L - count) * w0 + EPS);
#pragma unroll
        for (int i = 0; i < 2; ++i) {
            int r = q + kt + 64 * i;
            if (sv[i]) w[r * WP + q] = (wv[i] - w0) * inv;
        }
        if (kt == 0) adj[q] = w0 * inv;
    }
    __syncthreads();

    // ---- PV phase ----
    {
        int q = tid >> 6, h = (tid >> 5) & 1, dt = tid & 31;
        int mid = rlo + ((rhi - rlo + 1) >> 1);
        int ra = h ? mid : rlo;
        int rb = h ? rhi : mid;
        const float4* xb4 = (const float4*)(x + (size_t)b * L * D);
        float4 acc = {0.f, 0.f, 0.f, 0.f};
#pragma unroll 4
        for (int r = ra; r < rb; ++r) {
            float4 xv = xb4[(size_t)(row0 + r) * (D / 4) + dt];
            float ww = w[r * WP + q];
            acc.x += ww * xv.x; acc.y += ww * xv.y;
            acc.z += ww * xv.z; acc.w += ww * xv.w;
        }
        acc.x += __shfl_xor(acc.x, 32); acc.y += __shfl_xor(acc.y, 32);
        acc.z += __shfl_xor(acc.z, 32); acc.w += __shfl_xor(acc.w, 32);

        if (h == 0) {
            const float4* xp = (const float4*)(xpart + (size_t)(8 * b) * D);
            float sx = 0.f, sy = 0.f, sz = 0.f, sw = 0.f;
#pragma unroll
            for (int j = 0; j < 8; ++j) {
                float4 v = xp[j * 32 + dt];
                sx += v.x; sy += v.y; sz += v.z; sw += v.w;
            }
            float a = adj[q];
            float4 o = {acc.x + a * sx, acc.y + a * sy,
                        acc.z + a * sz, acc.w + a * sw};
            ((float4*)out)[((size_t)(b * L + t0 + q)) * (D / 4) + dt] = o;
        }
    }
}

extern "C" void kernel_launch(void* const* d_in, const int* in_sizes, int n_in,
                              void* d_out, int out_size, void* d_ws, size_t ws_size,
                              hipStream_t stream) {
    const float* x  = (const float*)d_in[0];
    const float* Wt = (const float*)d_in[1];
    const float* Wx = (const float*)d_in[2];
    const float* bh = (const float*)d_in[3];
    const float* Wa = (const float*)d_in[4];
    const float* ba = (const float*)d_in[5];
    float* out = (float*)d_out;

    float* ws    = (float*)d_ws;
    float* qd    = ws;                  // B*L = 4096 (c folded in)
    float* kd    = qd + B * L;          // 4096
    float* xpart = kd + B * L;          // 64 * 128 = 8192

    prep_kernel<<<64, 256, 0, stream>>>(x, Wt, Wx, bh, Wa, ba, qd, kd, xpart);
    attn_kernel<<<B * (L / T), 256, 0, stream>>>(x, qd, kd, xpart, out);
}